// Round 3
// baseline (374.738 us; speedup 1.0000x reference)
//
#include <hip/hip_runtime.h>

typedef float f32x4 __attribute__((ext_vector_type(4)));
typedef unsigned int u32x4 __attribute__((ext_vector_type(4)));

// ---------------- LDS layout (bytes) ----------------
#define LDS_WET     0        // [128][32]  bf16 :  8192
#define LDS_W2T     8192     // [128][136] bf16 : 34816
#define LDS_WC1T    43008    // [128][136] bf16 : 34816
#define LDS_ACT     77824    // [128][136] bf16 : 34816 (m1)
#define LDS_MBUF    112640   // [128][136] bf16 : 34816 (Hjs tile, then masked m)
#define LDS_F32     147456
// float sub-offsets (in floats): His 0, wd 128, b2 256, bc1 384, wc2 512,
// dsq 640, adjf 768, rel 896 (128*3), red 1280 (4*128), hrow 1792, hagg 1920,
// uvec 2048, xc 2176 (3*128), lnr 2560 (4)
#define LDS_BYTES  (147456 + 2564*4)   // 157712 < 160 KiB

__device__ __forceinline__ unsigned short f2bf(float f) {
  unsigned int u = __builtin_bit_cast(unsigned int, f);
  unsigned int r = u + 0x7FFFu + ((u >> 16) & 1u);
  return (unsigned short)(r >> 16);
}
__device__ __forceinline__ float bf2f(unsigned short hbits) {
  unsigned int u = ((unsigned int)hbits) << 16;
  return __builtin_bit_cast(float, u);
}
__device__ __forceinline__ unsigned int pk2(float lo, float hi) {
  return (unsigned int)f2bf(lo) | ((unsigned int)f2bf(hi) << 16);
}
__device__ __forceinline__ float silu_f(float xv) {
  float t = __builtin_amdgcn_exp2f(-1.44269504088896f * xv);  // exp(-x)
  return xv * __builtin_amdgcn_rcpf(1.0f + t);
}
__device__ __forceinline__ f32x4 mfma16(u32x4 a, u32x4 b, f32x4 c) {
  asm("v_mfma_f32_16x16x32_bf16 %0, %1, %2, %0" : "+v"(c) : "v"(a), "v"(b));
  return c;
}

// ---------------- precompute: His = h@W1[0:128]+b1, Hjs = h@W1[128:256] ----------------
__global__ void egnn_pre(const float* __restrict__ h,
                         const float* __restrict__ msg_w1,
                         const float* __restrict__ msg_b1,
                         float* __restrict__ hiw) {
  __shared__ float hr[128];
  const int row = blockIdx.x;      // b*384+n
  const int t = threadIdx.x;       // 0..255
  if (t < 128) hr[t] = h[(size_t)row*128 + t];
  __syncthreads();
  const int col = t & 127;
  const int base = (t < 128) ? 0 : 128;
  float s = (t < 128) ? msg_b1[col] : 0.0f;
  #pragma unroll 4
  for (int k = 0; k < 128; ++k) s += hr[k] * msg_w1[(size_t)(base + k)*128 + col];
  hiw[(size_t)row*256 + t] = s;
}

// ---------------- fused main kernel: one block per (b,i) ----------------
__launch_bounds__(512, 1)
__global__ void egnn_main(
    const float* __restrict__ h, const float* __restrict__ x,
    const float* __restrict__ eattr, const float* __restrict__ amask,
    const float* __restrict__ msg_w1, const float* __restrict__ msg_w2,
    const float* __restrict__ msg_b2, const float* __restrict__ node_w1,
    const float* __restrict__ node_b1, const float* __restrict__ node_w2,
    const float* __restrict__ node_b2, const float* __restrict__ coord_w1,
    const float* __restrict__ coord_b1, const float* __restrict__ coord_w2,
    const float* __restrict__ ln_g, const float* __restrict__ ln_b,
    const int* __restrict__ adj, const float* __restrict__ hiw,
    float* __restrict__ out)
{
  extern __shared__ char smem[];
  short* weT  = (short*)(smem + LDS_WET);
  short* w2T  = (short*)(smem + LDS_W2T);
  short* wc1T = (short*)(smem + LDS_WC1T);
  short* act  = (short*)(smem + LDS_ACT);
  short* mbuf = (short*)(smem + LDS_MBUF);
  float* fp   = (float*)(smem + LDS_F32);
  float* His  = fp;         float* wdv  = fp + 128;
  float* b2s  = fp + 256;   float* bc1s = fp + 384;
  float* wc2s = fp + 512;   float* dsq  = fp + 640;
  float* adjf = fp + 768;   float* rel  = fp + 896;
  float* red  = fp + 1280;  float* hrow = fp + 1792;
  float* hagg = fp + 1920;  float* uvec = fp + 2048;
  float* xc   = fp + 2176;  float* lnr  = fp + 2560;

  const int tid  = threadIdx.x;
  const int bi   = blockIdx.x;            // b*384 + i
  const int bb   = (bi / 384) * 384;      // b*384
  const int wave = tid >> 6;
  const int lane = tid & 63;
  const int g    = lane >> 4;
  const int lr   = lane & 15;

  // ---- stage weights (bf16, transposed [out][in]) ----
  for (int idx = tid; idx < 32*128; idx += 512) {
    int k = idx >> 7, d = idx & 127;
    weT[d*32 + k] = (short)f2bf(msg_w1[(size_t)(256 + k)*128 + d]);
  }
  for (int idx = tid; idx < 128*128; idx += 512) {
    int k = idx >> 7, d = idx & 127;
    w2T[d*136 + k]  = (short)f2bf(msg_w2[idx]);
    wc1T[d*136 + k] = (short)f2bf(coord_w1[idx]);
  }
  if (tid < 128) {
    His[tid]  = hiw[(size_t)bi*256 + tid];
    wdv[tid]  = msg_w1[288*128 + tid];
    b2s[tid]  = msg_b2[tid];
    bc1s[tid] = coord_b1[tid];
    wc2s[tid] = coord_w2[tid];
    hrow[tid] = h[(size_t)bi*128 + tid];
  }
  if (tid < 384) xc[tid] = 0.0f;
  const float xi0 = x[bi*3+0], xi1 = x[bi*3+1], xi2 = x[bi*3+2];
  float hacc = 0.0f;
  __syncthreads();

  for (int ch = 0; ch < 3; ++ch) {
    const int j0 = ch * 128;
    // ---- phase 0: Hjs tile (into mbuf), geometry, adjacency ----
    for (int idx = tid; idx < 128*128; idx += 512) {
      int r = idx >> 7, d = idx & 127;
      mbuf[r*136 + d] = (short)f2bf(hiw[(size_t)(bb + j0 + r)*256 + 128 + d]);
    }
    if (tid < 128) {
      int j = j0 + tid;
      float r0 = xi0 - x[(bb + j)*3 + 0];
      float r1 = xi1 - x[(bb + j)*3 + 1];
      float r2 = xi2 - x[(bb + j)*3 + 2];
      rel[tid*3+0] = r0; rel[tid*3+1] = r1; rel[tid*3+2] = r2;
      dsq[tid]  = r0*r0 + r1*r1 + r2*r2;
      adjf[tid] = (float)adj[(size_t)bi*384 + j];
    }
    __syncthreads();

    // ---- GEMM1: edge_attr@We + (His + Hjs + dsq*wd) folded into acc init ----
    {
      const int R = wave * 16;
      const float* ea = eattr + ((size_t)bi*384 + (size_t)(j0 + R + lr))*32 + g*8;
      float4 p0 = ((const float4*)ea)[0];
      float4 p1 = ((const float4*)ea)[1];
      u32x4 af;
      af[0] = pk2(p0.x, p0.y); af[1] = pk2(p0.z, p0.w);
      af[2] = pk2(p1.x, p1.y); af[3] = pk2(p1.z, p1.w);
      f32x4 acc[8];
      #pragma unroll
      for (int cf = 0; cf < 8; ++cf) {
        const int col = cf*16 + lr;
        const float hv = His[col], wv = wdv[col];
        #pragma unroll
        for (int r4 = 0; r4 < 4; ++r4) {
          const int row = R + 4*g + r4;
          acc[cf][r4] = hv + wv*dsq[row] + bf2f((unsigned short)mbuf[row*136 + col]);
        }
      }
      #pragma unroll
      for (int cf = 0; cf < 8; ++cf) {
        u32x4 bfr = *(const u32x4*)(weT + (cf*16 + lr)*32 + g*8);
        acc[cf] = mfma16(af, bfr, acc[cf]);
      }
      #pragma unroll
      for (int cf = 0; cf < 8; ++cf) {
        #pragma unroll
        for (int r4 = 0; r4 < 4; ++r4) {
          const int row = R + 4*g + r4, col = cf*16 + lr;
          act[row*136 + col] = (short)f2bf(silu_f(acc[cf][r4]));
        }
      }
    }
    __syncthreads();

    // ---- GEMM2: m = silu(m1@W2 + b2) * adj  -> mbuf (2x4 wave layout) ----
    {
      const int RB = (wave >> 1) * 32, CB = (wave & 1) * 64;
      f32x4 acc[2][4];
      #pragma unroll
      for (int cf = 0; cf < 4; ++cf) {
        const float bv = b2s[CB + cf*16 + lr];
        #pragma unroll
        for (int rf = 0; rf < 2; ++rf)
          #pragma unroll
          for (int r4 = 0; r4 < 4; ++r4) acc[rf][cf][r4] = bv;
      }
      #pragma unroll
      for (int kk = 0; kk < 4; ++kk) {
        u32x4 a0 = *(const u32x4*)(act + (RB + lr)*136 + kk*32 + g*8);
        u32x4 a1 = *(const u32x4*)(act + (RB + 16 + lr)*136 + kk*32 + g*8);
        #pragma unroll
        for (int cf = 0; cf < 4; ++cf) {
          u32x4 bfr = *(const u32x4*)(w2T + (CB + cf*16 + lr)*136 + kk*32 + g*8);
          acc[0][cf] = mfma16(a0, bfr, acc[0][cf]);
          acc[1][cf] = mfma16(a1, bfr, acc[1][cf]);
        }
      }
      #pragma unroll
      for (int rf = 0; rf < 2; ++rf)
        #pragma unroll
        for (int cf = 0; cf < 4; ++cf)
          #pragma unroll
          for (int r4 = 0; r4 < 4; ++r4) {
            const int row = RB + rf*16 + 4*g + r4, col = CB + cf*16 + lr;
            mbuf[row*136 + col] = (short)f2bf(silu_f(acc[rf][cf][r4]) * adjf[row]);
          }
    }
    __syncthreads();

    // ---- column-sum partial of masked m (h_agg) ----
    {
      const int d = tid & 127, q = tid >> 7;
      #pragma unroll 4
      for (int r = q*32; r < q*32 + 32; ++r)
        hacc += bf2f((unsigned short)mbuf[r*136 + d]);
    }

    // ---- scalar cw: cw[j] = sum_d silu(sum_k m[j,k]*wc1[k,d] + bc1[d]) * wc2[d]
    //      (bisection round: no MFMA, no act round-trip; reads only
    //       h-path-validated mbuf + wc1T) ----
    {
      const int j = tid & 127, q = tid >> 7;
      float cwq = 0.0f;
      if (adjf[j] != 0.0f) {
        float s[32];
        #pragma unroll
        for (int d = 0; d < 32; ++d) s[d] = bc1s[q*32 + d];
        for (int kk = 0; kk < 16; ++kk) {
          u32x4 mw = *(const u32x4*)(mbuf + j*136 + kk*8);
          float mk[8];
          #pragma unroll
          for (int t = 0; t < 4; ++t) {
            mk[2*t]   = bf2f((unsigned short)(mw[t] & 0xFFFFu));
            mk[2*t+1] = bf2f((unsigned short)(mw[t] >> 16));
          }
          #pragma unroll
          for (int d = 0; d < 32; ++d) {
            u32x4 ww = *(const u32x4*)(wc1T + (q*32 + d)*136 + kk*8);
            float a = 0.0f;
            #pragma unroll
            for (int t = 0; t < 4; ++t) {
              a += mk[2*t]   * bf2f((unsigned short)(ww[t] & 0xFFFFu));
              a += mk[2*t+1] * bf2f((unsigned short)(ww[t] >> 16));
            }
            s[d] += a;
          }
        }
        #pragma unroll
        for (int d = 0; d < 32; ++d) cwq += silu_f(s[d]) * wc2s[q*32 + d];
      }
      red[q*128 + j] = cwq;
    }
    __syncthreads();
    if (tid < 128) {
      const float cw = red[tid] + red[128+tid] + red[256+tid] + red[384+tid];
      const float dist = sqrtf(dsq[tid] + 1e-8f);
      const float f = cw / (dist + 1.0f) * adjf[tid];
      xc[tid]       += f * rel[tid*3+0];
      xc[128 + tid] += f * rel[tid*3+1];
      xc[256 + tid] += f * rel[tid*3+2];
    }
    __syncthreads();
  }

  // ---- block-level reductions ----
  { const int d = tid & 127, q = tid >> 7; red[q*128 + d] = hacc; }
  __syncthreads();
  if (tid < 128) hagg[tid] = red[tid] + red[128+tid] + red[256+tid] + red[384+tid];
  if (tid < 3) {
    float sx = 0.0f;
    #pragma unroll 8
    for (int j = 0; j < 128; ++j) sx += xc[tid*128 + j];
    out[98304 + (size_t)bi*3 + tid] = x[bi*3 + tid] + sx * amask[bi];
  }
  __syncthreads();

  // ---- node MLP layer 1: u = silu([h, hagg] @ node_w1 + b1) ----
  {
    const int d = tid & 127, q = tid >> 7;
    float s = 0.0f;
    for (int k = q*64; k < q*64 + 64; ++k) {
      const float inv = (k < 128) ? hrow[k] : hagg[k - 128];
      s += inv * node_w1[(size_t)k*128 + d];
    }
    red[q*128 + d] = s;
  }
  __syncthreads();
  if (tid < 128)
    uvec[tid] = silu_f(red[tid] + red[128+tid] + red[256+tid] + red[384+tid] + node_b1[tid]);
  __syncthreads();

  // ---- node MLP layer 2 + residual ----
  {
    const int d = tid & 127, q = tid >> 7;
    float s = 0.0f;
    for (int k = q*32; k < q*32 + 32; ++k) s += uvec[k] * node_w2[(size_t)k*128 + d];
    red[q*128 + d] = s;
  }
  __syncthreads();
  float y = 0.0f;
  if (tid < 128)
    y = hrow[tid] + red[tid] + red[128+tid] + red[256+tid] + red[384+tid] + node_b2[tid];

  // ---- LayerNorm across 128 values (2 waves active) ----
  float ssum = (tid < 128) ? y : 0.0f;
  #pragma unroll
  for (int mm = 1; mm < 64; mm <<= 1) ssum += __shfl_xor(ssum, mm, 64);
  if (tid < 128 && lane == 0) lnr[wave] = ssum;
  __syncthreads();
  const float mu = (lnr[0] + lnr[1]) * (1.0f/128.0f);
  float yc = (tid < 128) ? (y - mu) : 0.0f;
  float sq = yc * yc;
  #pragma unroll
  for (int mm = 1; mm < 64; mm <<= 1) sq += __shfl_xor(sq, mm, 64);
  if (tid < 128 && lane == 0) lnr[2 + wave] = sq;
  __syncthreads();
  if (tid < 128) {
    const float var = (lnr[2] + lnr[3]) * (1.0f/128.0f);
    out[(size_t)bi*128 + tid] = yc * rsqrtf(var + 1e-3f) * ln_g[tid] + ln_b[tid];
  }
}

extern "C" void kernel_launch(void* const* d_in, const int* in_sizes, int n_in,
                              void* d_out, int out_size, void* d_ws, size_t ws_size,
                              hipStream_t stream) {
  const float* h        = (const float*)d_in[0];
  const float* x        = (const float*)d_in[1];
  const float* eattr    = (const float*)d_in[2];
  const float* amask    = (const float*)d_in[3];
  const float* msg_w1   = (const float*)d_in[4];
  const float* msg_b1   = (const float*)d_in[5];
  const float* msg_w2   = (const float*)d_in[6];
  const float* msg_b2   = (const float*)d_in[7];
  const float* node_w1  = (const float*)d_in[8];
  const float* node_b1  = (const float*)d_in[9];
  const float* node_w2  = (const float*)d_in[10];
  const float* node_b2  = (const float*)d_in[11];
  const float* coord_w1 = (const float*)d_in[12];
  const float* coord_b1 = (const float*)d_in[13];
  const float* coord_w2 = (const float*)d_in[14];
  const float* ln_g     = (const float*)d_in[15];
  const float* ln_b     = (const float*)d_in[16];
  const int*   adj      = (const int*)d_in[17];
  float* out = (float*)d_out;
  float* hiw = (float*)d_ws;   // [768][256] f32 = 786432 B

  hipFuncSetAttribute((const void*)egnn_main,
                      hipFuncAttributeMaxDynamicSharedMemorySize, LDS_BYTES);

  egnn_pre<<<768, 256, 0, stream>>>(h, msg_w1, msg_b1, hiw);
  egnn_main<<<768, 512, LDS_BYTES, stream>>>(h, x, eattr, amask, msg_w1, msg_w2,
      msg_b2, node_w1, node_b1, node_w2, node_b2, coord_w1, coord_b1, coord_w2,
      ln_g, ln_b, adj, hiw, out);
}

// Round 4
// 124.688 us; speedup vs baseline: 3.0054x; 3.0054x over previous
//
#include <hip/hip_runtime.h>

typedef float f32x4 __attribute__((ext_vector_type(4)));
typedef unsigned int u32x4 __attribute__((ext_vector_type(4)));
typedef __bf16 bf16x8 __attribute__((ext_vector_type(8)));

// ---------------- LDS layout (bytes) ----------------
#define LDS_WET     0        // [128][32]  bf16 :  8192
#define LDS_W2T     8192     // [128][136] bf16 : 34816
#define LDS_WC1T    43008    // [128][136] bf16 : 34816
#define LDS_ACT     77824    // [128][136] bf16 : 34816 (m1; f32 cw partials scratch)
#define LDS_MBUF    112640   // [128][136] bf16 : 34816 (Hjs tile, then masked m)
#define LDS_F32     147456
// float sub-offsets (in floats): His 0, wd 128, b2 256, bc1 384, wc2 512,
// dsq 640, adjf 768, rel 896 (128*3), red 1280 (4*128), hrow 1792, hagg 1920,
// uvec 2048, xc 2176 (3*128), lnr 2560 (4)
#define LDS_BYTES  (147456 + 2564*4)   // 157712 < 160 KiB

__device__ __forceinline__ unsigned short f2bf(float f) {
  unsigned int u = __builtin_bit_cast(unsigned int, f);
  unsigned int r = u + 0x7FFFu + ((u >> 16) & 1u);
  return (unsigned short)(r >> 16);
}
__device__ __forceinline__ float bf2f(unsigned short hbits) {
  unsigned int u = ((unsigned int)hbits) << 16;
  return __builtin_bit_cast(float, u);
}
__device__ __forceinline__ unsigned int pk2(float lo, float hi) {
  return (unsigned int)f2bf(lo) | ((unsigned int)f2bf(hi) << 16);
}
__device__ __forceinline__ float silu_f(float xv) {
  float t = __builtin_amdgcn_exp2f(-1.44269504088896f * xv);  // exp(-x)
  return xv * __builtin_amdgcn_rcpf(1.0f + t);
}
__device__ __forceinline__ f32x4 mfma16(u32x4 a, u32x4 b, f32x4 c) {
  asm("v_mfma_f32_16x16x32_bf16 %0, %1, %2, %0" : "+v"(c) : "v"(a), "v"(b));
  return c;
}

// ---------------- precompute: His = h@W1[0:128]+b1, Hjs = h@W1[128:256] ----------------
__global__ void egnn_pre(const float* __restrict__ h,
                         const float* __restrict__ msg_w1,
                         const float* __restrict__ msg_b1,
                         float* __restrict__ hiw) {
  __shared__ float hr[128];
  const int row = blockIdx.x;      // b*384+n
  const int t = threadIdx.x;       // 0..255
  if (t < 128) hr[t] = h[(size_t)row*128 + t];
  __syncthreads();
  const int col = t & 127;
  const int base = (t < 128) ? 0 : 128;
  float s = (t < 128) ? msg_b1[col] : 0.0f;
  #pragma unroll 4
  for (int k = 0; k < 128; ++k) s += hr[k] * msg_w1[(size_t)(base + k)*128 + col];
  hiw[(size_t)row*256 + t] = s;
}

// ---------------- fused main kernel: one block per (b,i) ----------------
__launch_bounds__(512, 1)
__global__ void egnn_main(
    const float* __restrict__ h, const float* __restrict__ x,
    const float* __restrict__ eattr, const float* __restrict__ amask,
    const float* __restrict__ msg_w1, const float* __restrict__ msg_w2,
    const float* __restrict__ msg_b2, const float* __restrict__ node_w1,
    const float* __restrict__ node_b1, const float* __restrict__ node_w2,
    const float* __restrict__ node_b2, const float* __restrict__ coord_w1,
    const float* __restrict__ coord_b1, const float* __restrict__ coord_w2,
    const float* __restrict__ ln_g, const float* __restrict__ ln_b,
    const int* __restrict__ adj, const float* __restrict__ hiw,
    float* __restrict__ out)
{
  extern __shared__ char smem[];
  short* weT  = (short*)(smem + LDS_WET);
  short* w2T  = (short*)(smem + LDS_W2T);
  short* wc1T = (short*)(smem + LDS_WC1T);
  short* act  = (short*)(smem + LDS_ACT);
  short* mbuf = (short*)(smem + LDS_MBUF);
  float* fp   = (float*)(smem + LDS_F32);
  float* His  = fp;         float* wdv  = fp + 128;
  float* b2s  = fp + 256;   float* bc1s = fp + 384;
  float* wc2s = fp + 512;   float* dsq  = fp + 640;
  float* adjf = fp + 768;   float* rel  = fp + 896;
  float* red  = fp + 1280;  float* hrow = fp + 1792;
  float* hagg = fp + 1920;  float* uvec = fp + 2048;
  float* xc   = fp + 2176;  float* lnr  = fp + 2560;

  const int tid  = threadIdx.x;
  const int bi   = blockIdx.x;            // b*384 + i
  const int bb   = (bi / 384) * 384;      // b*384
  const int wave = tid >> 6;
  const int lane = tid & 63;
  const int g    = lane >> 4;
  const int lr   = lane & 15;

  // ---- stage weights (bf16, transposed [out][in]) ----
  for (int idx = tid; idx < 32*128; idx += 512) {
    int k = idx >> 7, d = idx & 127;
    weT[d*32 + k] = (short)f2bf(msg_w1[(size_t)(256 + k)*128 + d]);
  }
  for (int idx = tid; idx < 128*128; idx += 512) {
    int k = idx >> 7, d = idx & 127;
    w2T[d*136 + k]  = (short)f2bf(msg_w2[idx]);
    wc1T[d*136 + k] = (short)f2bf(coord_w1[idx]);
  }
  if (tid < 128) {
    His[tid]  = hiw[(size_t)bi*256 + tid];
    wdv[tid]  = msg_w1[288*128 + tid];
    b2s[tid]  = msg_b2[tid];
    bc1s[tid] = coord_b1[tid];
    wc2s[tid] = coord_w2[tid];
    hrow[tid] = h[(size_t)bi*128 + tid];
  }
  if (tid < 384) xc[tid] = 0.0f;
  const float xi0 = x[bi*3+0], xi1 = x[bi*3+1], xi2 = x[bi*3+2];
  float hacc = 0.0f;
  __syncthreads();

  for (int ch = 0; ch < 3; ++ch) {
    const int j0 = ch * 128;
    // ---- phase 0: Hjs tile (into mbuf), geometry, adjacency ----
    for (int idx = tid; idx < 128*128; idx += 512) {
      int r = idx >> 7, d = idx & 127;
      mbuf[r*136 + d] = (short)f2bf(hiw[(size_t)(bb + j0 + r)*256 + 128 + d]);
    }
    if (tid < 128) {
      int j = j0 + tid;
      float r0 = xi0 - x[(bb + j)*3 + 0];
      float r1 = xi1 - x[(bb + j)*3 + 1];
      float r2 = xi2 - x[(bb + j)*3 + 2];
      rel[tid*3+0] = r0; rel[tid*3+1] = r1; rel[tid*3+2] = r2;
      dsq[tid]  = r0*r0 + r1*r1 + r2*r2;
      adjf[tid] = (float)adj[(size_t)bi*384 + j];
    }
    __syncthreads();

    // ---- GEMM1: edge_attr@We + (His + Hjs + dsq*wd) folded into acc init ----
    {
      const int R = wave * 16;
      const float* ea = eattr + ((size_t)bi*384 + (size_t)(j0 + R + lr))*32 + g*8;
      float4 p0 = ((const float4*)ea)[0];
      float4 p1 = ((const float4*)ea)[1];
      u32x4 af;
      af[0] = pk2(p0.x, p0.y); af[1] = pk2(p0.z, p0.w);
      af[2] = pk2(p1.x, p1.y); af[3] = pk2(p1.z, p1.w);
      f32x4 acc[8];
      #pragma unroll
      for (int cf = 0; cf < 8; ++cf) {
        const int col = cf*16 + lr;
        const float hv = His[col], wv = wdv[col];
        #pragma unroll
        for (int r4 = 0; r4 < 4; ++r4) {
          const int row = R + 4*g + r4;
          acc[cf][r4] = hv + wv*dsq[row] + bf2f((unsigned short)mbuf[row*136 + col]);
        }
      }
      #pragma unroll
      for (int cf = 0; cf < 8; ++cf) {
        u32x4 bfr = *(const u32x4*)(weT + (cf*16 + lr)*32 + g*8);
        acc[cf] = mfma16(af, bfr, acc[cf]);
      }
      #pragma unroll
      for (int cf = 0; cf < 8; ++cf) {
        #pragma unroll
        for (int r4 = 0; r4 < 4; ++r4) {
          const int row = R + 4*g + r4, col = cf*16 + lr;
          act[row*136 + col] = (short)f2bf(silu_f(acc[cf][r4]));
        }
      }
    }
    __syncthreads();

    // ---- GEMM2: m = silu(m1@W2 + b2) * adj  -> mbuf (2x4 wave layout) ----
    {
      const int RB = (wave >> 1) * 32, CB = (wave & 1) * 64;
      f32x4 acc[2][4];
      #pragma unroll
      for (int cf = 0; cf < 4; ++cf) {
        const float bv = b2s[CB + cf*16 + lr];
        #pragma unroll
        for (int rf = 0; rf < 2; ++rf)
          #pragma unroll
          for (int r4 = 0; r4 < 4; ++r4) acc[rf][cf][r4] = bv;
      }
      #pragma unroll
      for (int kk = 0; kk < 4; ++kk) {
        u32x4 a0 = *(const u32x4*)(act + (RB + lr)*136 + kk*32 + g*8);
        u32x4 a1 = *(const u32x4*)(act + (RB + 16 + lr)*136 + kk*32 + g*8);
        #pragma unroll
        for (int cf = 0; cf < 4; ++cf) {
          u32x4 bfr = *(const u32x4*)(w2T + (CB + cf*16 + lr)*136 + kk*32 + g*8);
          acc[0][cf] = mfma16(a0, bfr, acc[0][cf]);
          acc[1][cf] = mfma16(a1, bfr, acc[1][cf]);
        }
      }
      #pragma unroll
      for (int rf = 0; rf < 2; ++rf)
        #pragma unroll
        for (int cf = 0; cf < 4; ++cf)
          #pragma unroll
          for (int r4 = 0; r4 < 4; ++r4) {
            const int row = RB + rf*16 + 4*g + r4, col = CB + cf*16 + lr;
            mbuf[row*136 + col] = (short)f2bf(silu_f(acc[rf][cf][r4]) * adjf[row]);
          }
    }
    __syncthreads();

    // ---- column-sum partial of masked m (h_agg) ----
    {
      const int d = tid & 127, q = tid >> 7;
      #pragma unroll 4
      for (int r = q*32; r < q*32 + 32; ++r)
        hacc += bf2f((unsigned short)mbuf[r*136 + d]);
    }

    // ---- GEMM3 (builtin MFMA): c1 = silu(m@Wc1 + bc1); partial cw in f32 ----
    {
      const int R = wave * 16;
      f32x4 acc[8];
      #pragma unroll
      for (int cf = 0; cf < 8; ++cf) {
        const float bv = bc1s[cf*16 + lr];
        #pragma unroll
        for (int r4 = 0; r4 < 4; ++r4) acc[cf][r4] = bv;
      }
      #pragma unroll
      for (int kk = 0; kk < 4; ++kk) {
        bf16x8 af = __builtin_bit_cast(bf16x8,
            *(const u32x4*)(mbuf + (R + lr)*136 + kk*32 + g*8));
        #pragma unroll
        for (int cf = 0; cf < 8; ++cf) {
          bf16x8 bfr = __builtin_bit_cast(bf16x8,
              *(const u32x4*)(wc1T + (cf*16 + lr)*136 + kk*32 + g*8));
          acc[cf] = __builtin_amdgcn_mfma_f32_16x16x32_bf16(af, bfr, acc[cf], 0, 0, 0);
        }
      }
      // per-lane partial over this lane's 16 cols for its 4 rows (f32, no bf16 trip)
      float p0 = 0.0f, p1 = 0.0f, p2 = 0.0f, p3 = 0.0f;
      #pragma unroll
      for (int cf = 0; cf < 8; ++cf) {
        const float wv = wc2s[cf*16 + lr];
        p0 += silu_f(acc[cf][0]) * wv; p1 += silu_f(acc[cf][1]) * wv;
        p2 += silu_f(acc[cf][2]) * wv; p3 += silu_f(acc[cf][3]) * wv;
      }
      float* actF = (float*)act;   // reuse m1 buffer as f32 scratch [128][20]
      const int rbase = R + 4*g;
      actF[(rbase+0)*20 + lr] = p0;
      actF[(rbase+1)*20 + lr] = p1;
      actF[(rbase+2)*20 + lr] = p2;
      actF[(rbase+3)*20 + lr] = p3;
    }
    __syncthreads();

    // ---- reduce 16 lane-partials per row -> cw[j] (validated red pattern) ----
    {
      const float* actF = (const float*)act;
      const int j = tid & 127, q = tid >> 7;
      red[q*128 + j] = actF[j*20 + q*4 + 0] + actF[j*20 + q*4 + 1]
                     + actF[j*20 + q*4 + 2] + actF[j*20 + q*4 + 3];
    }
    __syncthreads();
    if (tid < 128) {
      const float cw = red[tid] + red[128+tid] + red[256+tid] + red[384+tid];
      const float dist = sqrtf(dsq[tid] + 1e-8f);
      const float f = cw / (dist + 1.0f) * adjf[tid];
      xc[tid]       += f * rel[tid*3+0];
      xc[128 + tid] += f * rel[tid*3+1];
      xc[256 + tid] += f * rel[tid*3+2];
    }
    __syncthreads();
  }

  // ---- block-level reductions ----
  { const int d = tid & 127, q = tid >> 7; red[q*128 + d] = hacc; }
  __syncthreads();
  if (tid < 128) hagg[tid] = red[tid] + red[128+tid] + red[256+tid] + red[384+tid];
  if (tid < 3) {
    float sx = 0.0f;
    #pragma unroll 8
    for (int j = 0; j < 128; ++j) sx += xc[tid*128 + j];
    out[98304 + (size_t)bi*3 + tid] = x[bi*3 + tid] + sx * amask[bi];
  }
  __syncthreads();

  // ---- node MLP layer 1: u = silu([h, hagg] @ node_w1 + b1) ----
  {
    const int d = tid & 127, q = tid >> 7;
    float s = 0.0f;
    for (int k = q*64; k < q*64 + 64; ++k) {
      const float inv = (k < 128) ? hrow[k] : hagg[k - 128];
      s += inv * node_w1[(size_t)k*128 + d];
    }
    red[q*128 + d] = s;
  }
  __syncthreads();
  if (tid < 128)
    uvec[tid] = silu_f(red[tid] + red[128+tid] + red[256+tid] + red[384+tid] + node_b1[tid]);
  __syncthreads();

  // ---- node MLP layer 2 + residual ----
  {
    const int d = tid & 127, q = tid >> 7;
    float s = 0.0f;
    for (int k = q*32; k < q*32 + 32; ++k) s += uvec[k] * node_w2[(size_t)k*128 + d];
    red[q*128 + d] = s;
  }
  __syncthreads();
  float y = 0.0f;
  if (tid < 128)
    y = hrow[tid] + red[tid] + red[128+tid] + red[256+tid] + red[384+tid] + node_b2[tid];

  // ---- LayerNorm across 128 values (2 waves active) ----
  float ssum = (tid < 128) ? y : 0.0f;
  #pragma unroll
  for (int mm = 1; mm < 64; mm <<= 1) ssum += __shfl_xor(ssum, mm, 64);
  if (tid < 128 && lane == 0) lnr[wave] = ssum;
  __syncthreads();
  const float mu = (lnr[0] + lnr[1]) * (1.0f/128.0f);
  float yc = (tid < 128) ? (y - mu) : 0.0f;
  float sq = yc * yc;
  #pragma unroll
  for (int mm = 1; mm < 64; mm <<= 1) sq += __shfl_xor(sq, mm, 64);
  if (tid < 128 && lane == 0) lnr[2 + wave] = sq;
  __syncthreads();
  if (tid < 128) {
    const float var = (lnr[2] + lnr[3]) * (1.0f/128.0f);
    out[(size_t)bi*128 + tid] = yc * rsqrtf(var + 1e-3f) * ln_g[tid] + ln_b[tid];
  }
}

extern "C" void kernel_launch(void* const* d_in, const int* in_sizes, int n_in,
                              void* d_out, int out_size, void* d_ws, size_t ws_size,
                              hipStream_t stream) {
  const float* h        = (const float*)d_in[0];
  const float* x        = (const float*)d_in[1];
  const float* eattr    = (const float*)d_in[2];
  const float* amask    = (const float*)d_in[3];
  const float* msg_w1   = (const float*)d_in[4];
  const float* msg_b1   = (const float*)d_in[5];
  const float* msg_w2   = (const float*)d_in[6];
  const float* msg_b2   = (const float*)d_in[7];
  const float* node_w1  = (const float*)d_in[8];
  const float* node_b1  = (const float*)d_in[9];
  const float* node_w2  = (const float*)d_in[10];
  const float* node_b2  = (const float*)d_in[11];
  const float* coord_w1 = (const float*)d_in[12];
  const float* coord_b1 = (const float*)d_in[13];
  const float* coord_w2 = (const float*)d_in[14];
  const float* ln_g     = (const float*)d_in[15];
  const float* ln_b     = (const float*)d_in[16];
  const int*   adj      = (const int*)d_in[17];
  float* out = (float*)d_out;
  float* hiw = (float*)d_ws;   // [768][256] f32 = 786432 B

  hipFuncSetAttribute((const void*)egnn_main,
                      hipFuncAttributeMaxDynamicSharedMemorySize, LDS_BYTES);

  egnn_pre<<<768, 256, 0, stream>>>(h, msg_w1, msg_b1, hiw);
  egnn_main<<<768, 512, LDS_BYTES, stream>>>(h, x, eattr, amask, msg_w1, msg_w2,
      msg_b2, node_w1, node_b1, node_w2, node_b2, coord_w1, coord_b1, coord_w2,
      ln_g, ln_b, adj, hiw, out);
}

// Round 5
// 112.514 us; speedup vs baseline: 3.3306x; 1.1082x over previous
//
#include <hip/hip_runtime.h>

typedef float f32x4 __attribute__((ext_vector_type(4)));
typedef unsigned int u32x4 __attribute__((ext_vector_type(4)));
typedef unsigned int u32x2 __attribute__((ext_vector_type(2)));
typedef __bf16 bf16x8 __attribute__((ext_vector_type(8)));

// ---------------- LDS layout (bytes) ----------------
#define LDS_WET   0        // [128][40]  bf16 : 10240  (We^T: [d][k], K=32)
#define LDS_W2T   10240    // [128][136] bf16 : 34816  (W2^T: [d][k])
#define LDS_WC1T  45056    // [128][136] bf16 : 34816  (Wc1^T: [d][k])
#define LDS_ACT   79872    // [128][136] bf16 : 34816  (m1 [j][k]; tail f32 scratch)
#define LDS_MBUF  114688   // [128][132] bf16 : 33792  (Hjs tile -> masked m, [j][d])
#define LDS_EBUF  148480   // [128][40]  bf16 : 10240  (eattr tile [j][k])
#define LDS_FP    158720   // 1024 f32 : 4096
// fp floats: dsq 0, adjf 128, rel 256 (384), bc1s 640, wc2s 768, hrow 896
#define LDS_BYTES 162816   // <= 163840

__device__ __forceinline__ unsigned short f2bf(float f) {
  unsigned int u = __builtin_bit_cast(unsigned int, f);
  unsigned int r = u + 0x7FFFu + ((u >> 16) & 1u);
  return (unsigned short)(r >> 16);
}
__device__ __forceinline__ float bf2f(unsigned short hbits) {
  unsigned int u = ((unsigned int)hbits) << 16;
  return __builtin_bit_cast(float, u);
}
__device__ __forceinline__ unsigned int pk2(float lo, float hi) {
  return (unsigned int)f2bf(lo) | ((unsigned int)f2bf(hi) << 16);
}
__device__ __forceinline__ float silu_f(float xv) {
  float t = __builtin_amdgcn_exp2f(-1.44269504088896f * xv);  // exp(-x)
  return xv * __builtin_amdgcn_rcpf(1.0f + t);
}
__device__ __forceinline__ f32x4 mfma16(u32x4 a, u32x4 b, f32x4 c) {
  return __builtin_amdgcn_mfma_f32_16x16x32_bf16(
      __builtin_bit_cast(bf16x8, a), __builtin_bit_cast(bf16x8, b), c, 0, 0, 0);
}

// ---- precompute: his = h@W1[0:128]+b1 (f32), hjw = bf16(h@W1[128:256]) ----
__global__ void egnn_pre(const float* __restrict__ h,
                         const float* __restrict__ msg_w1,
                         const float* __restrict__ msg_b1,
                         float* __restrict__ his,
                         unsigned short* __restrict__ hjw) {
  __shared__ float hr[128];
  const int row = blockIdx.x;      // b*384+n
  const int t = threadIdx.x;       // 0..255
  if (t < 128) hr[t] = h[(size_t)row*128 + t];
  __syncthreads();
  const int col = t & 127;
  const int base = (t < 128) ? 0 : 128;
  float s = (t < 128) ? msg_b1[col] : 0.0f;
  #pragma unroll 4
  for (int k = 0; k < 128; ++k) s += hr[k] * msg_w1[(size_t)(base + k)*128 + col];
  if (t < 128) his[(size_t)row*128 + col] = s;
  else         hjw[(size_t)row*128 + col] = f2bf(s);
}

// ---------------- fused main kernel: one block per (b,i) ----------------
__launch_bounds__(512, 1)
__global__ void egnn_main(
    const float* __restrict__ h, const float* __restrict__ x,
    const float* __restrict__ eattr, const float* __restrict__ amask,
    const float* __restrict__ msg_w1, const float* __restrict__ msg_w2,
    const float* __restrict__ msg_b2, const float* __restrict__ node_w1,
    const float* __restrict__ node_b1, const float* __restrict__ node_w2,
    const float* __restrict__ node_b2, const float* __restrict__ coord_w1,
    const float* __restrict__ coord_b1, const float* __restrict__ coord_w2,
    const float* __restrict__ ln_g, const float* __restrict__ ln_b,
    const int* __restrict__ adj, const float* __restrict__ his,
    const unsigned short* __restrict__ hjw, float* __restrict__ out)
{
  extern __shared__ char smem[];
  short* weT  = (short*)(smem + LDS_WET);
  short* w2T  = (short*)(smem + LDS_W2T);
  short* wc1T = (short*)(smem + LDS_WC1T);
  short* act  = (short*)(smem + LDS_ACT);
  short* mbuf = (short*)(smem + LDS_MBUF);
  short* ebuf = (short*)(smem + LDS_EBUF);
  float* fp   = (float*)(smem + LDS_FP);
  float* dsq  = fp;          float* adjf = fp + 128;
  float* rel  = fp + 256;    float* bc1s = fp + 640;
  float* wc2s = fp + 768;    float* hrow = fp + 896;

  const int tid  = threadIdx.x;
  const int bi   = blockIdx.x;            // b*384 + i
  const int bb   = (bi / 384) * 384;
  const int wave = tid >> 6;
  const int lane = tid & 63;
  const int g    = lane >> 4;
  const int lr   = lane & 15;
  const int R  = wave * 16;               // GEMM1 d-rows / GEMM3 j-block
  const int RB = (wave >> 1) * 32;        // GEMM2 d-rows
  const int CB = (wave & 1) * 64;         // GEMM2 j-cols
  const int d4 = R + 4*g;                 // this lane's 4 consecutive d (GEMM1)
  const int jW = R + lr;                  // this lane's j (GEMM3)

  // ---- stage weights (bf16, [out_d][k]) ----
  for (int idx = tid; idx < 32*128; idx += 512) {
    int k = idx >> 7, d = idx & 127;
    weT[d*40 + k] = (short)f2bf(msg_w1[(size_t)(256 + k)*128 + d]);
  }
  for (int idx = tid; idx < 128*128; idx += 512) {
    int k = idx >> 7, d = idx & 127;
    w2T[d*136 + k]  = (short)f2bf(msg_w2[idx]);
    wc1T[d*136 + k] = (short)f2bf(coord_w1[idx]);
  }
  if (tid < 128) {
    bc1s[tid] = coord_b1[tid];
    wc2s[tid] = coord_w2[tid];
    hrow[tid] = h[(size_t)bi*128 + tid];
  }
  // per-lane constants (fixed d-ranges across chunks)
  const float4 His4 = *(const float4*)(his + (size_t)bi*128 + d4);
  const float4 wd4  = *(const float4*)(msg_w1 + 288*128 + d4);
  const float4 b2a  = *(const float4*)(msg_b2 + RB + 4*g);
  const float4 b2b  = *(const float4*)(msg_b2 + RB + 16 + 4*g);
  const float xi0 = x[bi*3+0], xi1 = x[bi*3+1], xi2 = x[bi*3+2];
  float hacc_v[8];
  #pragma unroll
  for (int v = 0; v < 8; ++v) hacc_v[v] = 0.0f;
  float xc0 = 0.0f, xc1 = 0.0f, xc2 = 0.0f;
  __syncthreads();

  for (int ch = 0; ch < 3; ++ch) {
    const int j0 = ch * 128;
    // ---- stage: Hjs tile (pure copy, pre-converted bf16), eattr tile, geometry ----
    #pragma unroll
    for (int it = 0; it < 4; ++it) {
      int idx = tid + it*512;
      int r = idx >> 4, s = idx & 15;
      u32x4 v = *(const u32x4*)(hjw + ((size_t)(bb + j0 + r))*128 + s*8);
      *(u32x2*)(mbuf + r*132 + s*8)     = (u32x2){v[0], v[1]};
      *(u32x2*)(mbuf + r*132 + s*8 + 4) = (u32x2){v[2], v[3]};
    }
    #pragma unroll
    for (int it = 0; it < 2; ++it) {
      int idx = tid + it*512;
      int j = idx >> 3, s = idx & 7;
      float4 p = *(const float4*)(eattr + ((size_t)bi*384 + (size_t)(j0 + j))*32 + s*4);
      *(u32x2*)(ebuf + j*40 + s*4) = (u32x2){pk2(p.x, p.y), pk2(p.z, p.w)};
    }
    if (tid < 128) {
      int j = j0 + tid;
      float r0 = xi0 - x[(bb + j)*3 + 0];
      float r1 = xi1 - x[(bb + j)*3 + 1];
      float r2 = xi2 - x[(bb + j)*3 + 2];
      rel[tid*3+0] = r0; rel[tid*3+1] = r1; rel[tid*3+2] = r2;
      dsq[tid]  = r0*r0 + r1*r1 + r2*r2;
      adjf[tid] = (float)adj[(size_t)bi*384 + j];
    }
    __syncthreads();

    // ---- GEMM1 (C^T): act[j][d] = silu(A=We^T rows d, B=eattr rows j, + init) ----
    {
      u32x4 aw = *(const u32x4*)(weT + (R + lr)*40 + g*8);
      #pragma unroll
      for (int cf = 0; cf < 8; ++cf) {
        const int j = cf*16 + lr;
        u32x4 be = *(const u32x4*)(ebuf + j*40 + g*8);
        u32x2 hj = *(const u32x2*)(mbuf + j*132 + d4);
        const float dq = dsq[j];
        f32x4 acc;
        acc[0] = His4.x + dq*wd4.x + bf2f((unsigned short)(hj[0] & 0xFFFFu));
        acc[1] = His4.y + dq*wd4.y + bf2f((unsigned short)(hj[0] >> 16));
        acc[2] = His4.z + dq*wd4.z + bf2f((unsigned short)(hj[1] & 0xFFFFu));
        acc[3] = His4.w + dq*wd4.w + bf2f((unsigned short)(hj[1] >> 16));
        acc = mfma16(aw, be, acc);
        *(u32x2*)(act + j*136 + d4) =
            (u32x2){pk2(silu_f(acc[0]), silu_f(acc[1])),
                    pk2(silu_f(acc[2]), silu_f(acc[3]))};
      }
    }
    __syncthreads();

    // ---- GEMM2 (C^T): m[j][d] = silu(A=W2^T, B=m1 rows j, +b2)*adj; hacc in-reg ----
    {
      f32x4 acc2[2][4];
      #pragma unroll
      for (int cf = 0; cf < 4; ++cf) {
        acc2[0][cf] = (f32x4){b2a.x, b2a.y, b2a.z, b2a.w};
        acc2[1][cf] = (f32x4){b2b.x, b2b.y, b2b.z, b2b.w};
      }
      #pragma unroll
      for (int kk = 0; kk < 4; ++kk) {
        u32x4 a0 = *(const u32x4*)(w2T + (RB + lr)*136 + kk*32 + g*8);
        u32x4 a1 = *(const u32x4*)(w2T + (RB + 16 + lr)*136 + kk*32 + g*8);
        #pragma unroll
        for (int cf = 0; cf < 4; ++cf) {
          u32x4 bfr = *(const u32x4*)(act + (CB + cf*16 + lr)*136 + kk*32 + g*8);
          acc2[0][cf] = mfma16(a0, bfr, acc2[0][cf]);
          acc2[1][cf] = mfma16(a1, bfr, acc2[1][cf]);
        }
      }
      #pragma unroll
      for (int cf = 0; cf < 4; ++cf) {
        const int j = CB + cf*16 + lr;
        const float aj = adjf[j];
        #pragma unroll
        for (int rf = 0; rf < 2; ++rf) {
          float v0 = silu_f(acc2[rf][cf][0]) * aj;
          float v1 = silu_f(acc2[rf][cf][1]) * aj;
          float v2 = silu_f(acc2[rf][cf][2]) * aj;
          float v3 = silu_f(acc2[rf][cf][3]) * aj;
          hacc_v[rf*4+0] += v0; hacc_v[rf*4+1] += v1;
          hacc_v[rf*4+2] += v2; hacc_v[rf*4+3] += v3;
          *(u32x2*)(mbuf + j*132 + RB + rf*16 + 4*g) =
              (u32x2){pk2(v0, v1), pk2(v2, v3)};
        }
      }
    }
    __syncthreads();

    // ---- GEMM3 (C^T): c1[d2][j]; cw via in-wave g-reduce; xc in-reg ----
    {
      f32x4 acc3[8];
      #pragma unroll
      for (int rf = 0; rf < 8; ++rf)
        acc3[rf] = *(const f32x4*)(bc1s + rf*16 + 4*g);
      #pragma unroll
      for (int kk = 0; kk < 4; ++kk) {
        u32x2 blo = *(const u32x2*)(mbuf + jW*132 + kk*32 + g*8);
        u32x2 bhi = *(const u32x2*)(mbuf + jW*132 + kk*32 + g*8 + 4);
        u32x4 bm = (u32x4){blo[0], blo[1], bhi[0], bhi[1]};
        #pragma unroll
        for (int rf = 0; rf < 8; ++rf) {
          u32x4 af = *(const u32x4*)(wc1T + (rf*16 + lr)*136 + kk*32 + g*8);
          acc3[rf] = mfma16(af, bm, acc3[rf]);
        }
      }
      float cwp = 0.0f;
      #pragma unroll
      for (int rf = 0; rf < 8; ++rf) {
        f32x4 wv = *(const f32x4*)(wc2s + rf*16 + 4*g);
        cwp += silu_f(acc3[rf][0]) * wv[0];
        cwp += silu_f(acc3[rf][1]) * wv[1];
        cwp += silu_f(acc3[rf][2]) * wv[2];
        cwp += silu_f(acc3[rf][3]) * wv[3];
      }
      cwp += __shfl_xor(cwp, 16, 64);
      cwp += __shfl_xor(cwp, 32, 64);
      if (lane < 16) {
        const float dist = sqrtf(dsq[jW] + 1e-8f);
        const float f = cwp * __builtin_amdgcn_rcpf(dist + 1.0f) * adjf[jW];
        xc0 += f * rel[jW*3+0];
        xc1 += f * rel[jW*3+1];
        xc2 += f * rel[jW*3+2];
      }
    }
    __syncthreads();
  }

  // ---- tail: hacc reduce (shuffle over lr) + xc publish ----
  #pragma unroll
  for (int v = 0; v < 8; ++v) {
    hacc_v[v] += __shfl_xor(hacc_v[v], 1, 64);
    hacc_v[v] += __shfl_xor(hacc_v[v], 2, 64);
    hacc_v[v] += __shfl_xor(hacc_v[v], 4, 64);
    hacc_v[v] += __shfl_xor(hacc_v[v], 8, 64);
  }
  float* actF  = (float*)act;     // act is dead after last GEMM2; reuse as f32 scratch
  float* hpart = actF;            // 256
  float* xcf   = actF + 256;      // 384
  float* red   = actF + 640;      // 512
  float* hagg  = actF + 1152;     // 128
  float* uvec  = actF + 1280;     // 128
  float* lnr   = actF + 1408;     // 4
  if (lr == 0) {
    #pragma unroll
    for (int rf = 0; rf < 2; ++rf)
      #pragma unroll
      for (int r = 0; r < 4; ++r)
        hpart[(wave & 1)*128 + RB + rf*16 + 4*g + r] = hacc_v[rf*4 + r];
  }
  if (lane < 16) {
    xcf[jW] = xc0; xcf[128 + jW] = xc1; xcf[256 + jW] = xc2;
  }
  __syncthreads();
  if (tid < 128) hagg[tid] = hpart[tid] + hpart[128 + tid];
  if (tid < 3) {
    float sx = 0.0f;
    #pragma unroll 8
    for (int j = 0; j < 128; ++j) sx += xcf[tid*128 + j];
    out[98304 + (size_t)bi*3 + tid] = x[bi*3 + tid] + sx * amask[bi];
  }
  __syncthreads();

  // ---- node MLP layer 1: u = silu([h, hagg] @ node_w1 + b1) ----
  {
    const int d = tid & 127, q = tid >> 7;
    float s = 0.0f;
    for (int k = q*64; k < q*64 + 64; ++k) {
      const float inv = (k < 128) ? hrow[k] : hagg[k - 128];
      s += inv * node_w1[(size_t)k*128 + d];
    }
    red[q*128 + d] = s;
  }
  __syncthreads();
  if (tid < 128)
    uvec[tid] = silu_f(red[tid] + red[128+tid] + red[256+tid] + red[384+tid] + node_b1[tid]);
  __syncthreads();

  // ---- node MLP layer 2 + residual ----
  {
    const int d = tid & 127, q = tid >> 7;
    float s = 0.0f;
    for (int k = q*32; k < q*32 + 32; ++k) s += uvec[k] * node_w2[(size_t)k*128 + d];
    red[q*128 + d] = s;
  }
  __syncthreads();
  float y = 0.0f;
  if (tid < 128)
    y = hrow[tid] + red[tid] + red[128+tid] + red[256+tid] + red[384+tid] + node_b2[tid];

  // ---- LayerNorm across 128 values (2 waves active) ----
  float ssum = (tid < 128) ? y : 0.0f;
  #pragma unroll
  for (int mm = 1; mm < 64; mm <<= 1) ssum += __shfl_xor(ssum, mm, 64);
  if (tid < 128 && lane == 0) lnr[wave] = ssum;
  __syncthreads();
  const float mu = (lnr[0] + lnr[1]) * (1.0f/128.0f);
  float yc = (tid < 128) ? (y - mu) : 0.0f;
  float sq = yc * yc;
  #pragma unroll
  for (int mm = 1; mm < 64; mm <<= 1) sq += __shfl_xor(sq, mm, 64);
  if (tid < 128 && lane == 0) lnr[2 + wave] = sq;
  __syncthreads();
  if (tid < 128) {
    const float var = (lnr[2] + lnr[3]) * (1.0f/128.0f);
    out[(size_t)bi*128 + tid] = yc * rsqrtf(var + 1e-3f) * ln_g[tid] + ln_b[tid];
  }
}

extern "C" void kernel_launch(void* const* d_in, const int* in_sizes, int n_in,
                              void* d_out, int out_size, void* d_ws, size_t ws_size,
                              hipStream_t stream) {
  const float* h        = (const float*)d_in[0];
  const float* x        = (const float*)d_in[1];
  const float* eattr    = (const float*)d_in[2];
  const float* amask    = (const float*)d_in[3];
  const float* msg_w1   = (const float*)d_in[4];
  const float* msg_b1   = (const float*)d_in[5];
  const float* msg_w2   = (const float*)d_in[6];
  const float* msg_b2   = (const float*)d_in[7];
  const float* node_w1  = (const float*)d_in[8];
  const float* node_b1  = (const float*)d_in[9];
  const float* node_w2  = (const float*)d_in[10];
  const float* node_b2  = (const float*)d_in[11];
  const float* coord_w1 = (const float*)d_in[12];
  const float* coord_b1 = (const float*)d_in[13];
  const float* coord_w2 = (const float*)d_in[14];
  const float* ln_g     = (const float*)d_in[15];
  const float* ln_b     = (const float*)d_in[16];
  const int*   adj      = (const int*)d_in[17];
  float* out = (float*)d_out;
  float* his = (float*)d_ws;                                        // 768*128*4 = 393216 B
  unsigned short* hjw = (unsigned short*)((char*)d_ws + 393216);    // 768*128*2 = 196608 B

  hipFuncSetAttribute((const void*)egnn_main,
                      hipFuncAttributeMaxDynamicSharedMemorySize, LDS_BYTES);

  egnn_pre<<<768, 256, 0, stream>>>(h, msg_w1, msg_b1, his, hjw);
  egnn_main<<<768, 512, LDS_BYTES, stream>>>(h, x, eattr, amask, msg_w1, msg_w2,
      msg_b2, node_w1, node_b1, node_w2, node_b2, coord_w1, coord_b1, coord_w2,
      ln_g, ln_b, adj, his, hjw, out);
}